// Round 1
// baseline (425.755 us; speedup 1.0000x reference)
//
#include <hip/hip_runtime.h>

#define N_NODES 100000
#define N_EDGES 3200000
#define D_NODE 128
#define D_EDGE 16

// out[i] = w_node * nodes[i,0] + b_node   (must overwrite 0xAA poison)
__global__ void tmp_init_out(const float* __restrict__ nodes,
                             const float* __restrict__ w_node,
                             const float* __restrict__ b_node,
                             float* __restrict__ out) {
    int i = blockIdx.x * blockDim.x + threadIdx.x;
    if (i < N_NODES) {
        out[i] = w_node[0] * nodes[(size_t)i * D_NODE] + b_node[0];
    }
}

// For each edge e: atomicAdd(out[recv[e]], w_edge*edges[e,0] + w_node*nodes[send[e],0])
// 4 edges per thread: int4 index loads are fully coalesced; edge column-0 loads
// are stride-64B (cacheline-granular fetch is unavoidable given the layout).
__global__ void tmp_edge_scatter(const float* __restrict__ nodes,
                                 const float* __restrict__ edges,
                                 const int*   __restrict__ senders,
                                 const int*   __restrict__ receivers,
                                 const float* __restrict__ w_node,
                                 const float* __restrict__ w_edge,
                                 float* __restrict__ out) {
    const float wn = w_node[0];
    const float we = w_edge[0];
    int base = (blockIdx.x * blockDim.x + threadIdx.x) * 4;
    if (base + 3 < N_EDGES) {
        int4 s = *(const int4*)(senders + base);
        int4 r = *(const int4*)(receivers + base);
        float e0 = edges[(size_t)(base + 0) * D_EDGE];
        float e1 = edges[(size_t)(base + 1) * D_EDGE];
        float e2 = edges[(size_t)(base + 2) * D_EDGE];
        float e3 = edges[(size_t)(base + 3) * D_EDGE];
        float m0 = we * e0 + wn * nodes[(size_t)s.x * D_NODE];
        float m1 = we * e1 + wn * nodes[(size_t)s.y * D_NODE];
        float m2 = we * e2 + wn * nodes[(size_t)s.z * D_NODE];
        float m3 = we * e3 + wn * nodes[(size_t)s.w * D_NODE];
        atomicAdd(&out[r.x], m0);
        atomicAdd(&out[r.y], m1);
        atomicAdd(&out[r.z], m2);
        atomicAdd(&out[r.w], m3);
    } else {
        // tail (N_EDGES % 4 == 0, so normally unreachable; kept for safety)
        for (int e = base; e < N_EDGES; ++e) {
            float m = we * edges[(size_t)e * D_EDGE]
                    + wn * nodes[(size_t)senders[e] * D_NODE];
            atomicAdd(&out[receivers[e]], m);
        }
    }
}

extern "C" void kernel_launch(void* const* d_in, const int* in_sizes, int n_in,
                              void* d_out, int out_size, void* d_ws, size_t ws_size,
                              hipStream_t stream) {
    const float* nodes     = (const float*)d_in[0];
    const float* edges     = (const float*)d_in[1];
    const int*   senders   = (const int*)d_in[2];
    const int*   receivers = (const int*)d_in[3];
    const float* w_node    = (const float*)d_in[4];
    const float* w_edge    = (const float*)d_in[5];
    const float* b_node    = (const float*)d_in[6];
    float* out = (float*)d_out;

    {
        int threads = 256;
        int blocks = (N_NODES + threads - 1) / threads;
        tmp_init_out<<<blocks, threads, 0, stream>>>(nodes, w_node, b_node, out);
    }
    {
        int threads = 256;
        int n_thr = N_EDGES / 4;  // 800000, exact
        int blocks = (n_thr + threads - 1) / threads;
        tmp_edge_scatter<<<blocks, threads, 0, stream>>>(
            nodes, edges, senders, receivers, w_node, w_edge, out);
    }
}